// Round 1
// baseline (534.578 us; speedup 1.0000x reference)
//
#include <hip/hip_runtime.h>
#include <hip/hip_bf16.h>

typedef __attribute__((ext_vector_type(8))) short bf16x8;
typedef __attribute__((ext_vector_type(4))) float f32x4;

// ---------------------------------------------------------------- pool: xbar[b][c][t] = mean_hw x
__global__ __launch_bounds__(256) void pool_kernel(const float* __restrict__ x,
                                                   float* __restrict__ xbar) {
    int row = blockIdx.x * 16 + (threadIdx.x >> 4);   // (b*1024+c)*8+t
    int j = threadIdx.x & 15;
    const float4* p = (const float4*)(x + (size_t)row * 128);
    float4 a = p[j * 2], b2 = p[j * 2 + 1];
    float s = a.x + a.y + a.z + a.w + b2.x + b2.y + b2.z + b2.w;
    s += __shfl_xor(s, 1); s += __shfl_xor(s, 2);
    s += __shfl_xor(s, 4); s += __shfl_xor(s, 8);
    if (j == 0) xbar[row] = s * (1.0f / 128.0f);
}

// ------------------------------------------- theta/phi: [b][ic][t] = W @ xbar[b][:][t] + bias
__global__ __launch_bounds__(256) void thetaphi_kernel(
        const float* __restrict__ xbar,
        const float* __restrict__ tw, const float* __restrict__ tb,
        const float* __restrict__ pw, const float* __restrict__ pb,
        float* __restrict__ theta, float* __restrict__ phi) {
    int which = blockIdx.x & 1;
    int icc = (blockIdx.x >> 1) & 15;
    int b = blockIdx.x >> 5;
    const float* w = which ? pw : tw;
    const float* bias = which ? pb : tb;
    float* out = which ? phi : theta;
    __shared__ float xs[8192];
    for (int i = threadIdx.x; i < 8192; i += 256) xs[i] = xbar[b * 8192 + i];
    __syncthreads();
    int icl = threadIdx.x >> 3;
    int t = threadIdx.x & 7;
    int ic = icc * 32 + icl;
    const float* wr = w + (size_t)ic * 1024;
    float acc = 0.0f;
    #pragma unroll 8
    for (int k = 0; k < 1024; k++) acc += wr[k] * xs[k * 8 + t];
    out[((size_t)b * 512 + ic) * 8 + t] = acc + bias[ic];
}

// ------------------------------------------------------- attn[b][t][s] = softmax_s(theta.phi)
__global__ __launch_bounds__(64) void attn_kernel(const float* __restrict__ theta,
                                                  const float* __restrict__ phi,
                                                  float* __restrict__ attn) {
    __shared__ float th[4096], ph[4096];
    int b = blockIdx.x, lane = threadIdx.x;
    for (int i = lane; i < 4096; i += 64) {
        th[i] = theta[(size_t)b * 4096 + i];
        ph[i] = phi[(size_t)b * 4096 + i];
    }
    __syncthreads();
    int t = lane >> 3, s = lane & 7;
    float f = 0.0f;
    #pragma unroll 8
    for (int ic = 0; ic < 512; ic++) f += th[ic * 8 + t] * ph[ic * 8 + s];
    float m = f;
    m = fmaxf(m, __shfl_xor(m, 1));
    m = fmaxf(m, __shfl_xor(m, 2));
    m = fmaxf(m, __shfl_xor(m, 4));
    float e = __expf(f - m);
    float sum = e;
    sum += __shfl_xor(sum, 1); sum += __shfl_xor(sum, 2); sum += __shfl_xor(sum, 4);
    attn[b * 64 + lane] = e / sum;
}

// ------------------------------------------------- M[c][cin] = sum_ic w_w[c][ic]*g_w[ic][cin]
__global__ __launch_bounds__(256) void prepM_kernel(const float* __restrict__ ww,
                                                    const float* __restrict__ gw,
                                                    __hip_bfloat16* __restrict__ M) {
    __shared__ float wsh[16 * 512];
    int c0 = (blockIdx.x >> 2) * 16;
    int col = (blockIdx.x & 3) * 256 + threadIdx.x;
    for (int i = threadIdx.x; i < 16 * 512; i += 256) wsh[i] = ww[(size_t)c0 * 512 + i];
    __syncthreads();
    float acc[16] = {};
    for (int k = 0; k < 512; k++) {
        float g = gw[(size_t)k * 1024 + col];
        #pragma unroll
        for (int r = 0; r < 16; r++) acc[r] += wsh[r * 512 + k] * g;
    }
    for (int r = 0; r < 16; r++)
        M[(size_t)(c0 + r) * 1024 + col] = __float2bfloat16(acc[r]);
}

// ------------------------------------------- per-channel epilogue constants inv[c], shift[c]
__global__ __launch_bounds__(256) void prepbias_kernel(
        const float* __restrict__ ww, const float* __restrict__ gb,
        const float* __restrict__ wb, const float* __restrict__ gamma,
        const float* __restrict__ beta, const float* __restrict__ mean,
        const float* __restrict__ var, float* __restrict__ inv,
        float* __restrict__ shift) {
    int c = blockIdx.x * 256 + threadIdx.x;
    float cb = wb[c];
    const float* wr = ww + (size_t)c * 512;
    for (int k = 0; k < 512; k++) cb += wr[k] * gb[k];
    float iv = gamma[c] * rsqrtf(var[c] + 1e-5f);
    inv[c] = iv;
    shift[c] = cb * iv + beta[c] - mean[c] * iv;
}

// ------------- mix + transpose: xm_t[b][t*128+hw][c] (bf16) = sum_s attn[b][t][s]*x[b][c][s][hw]
__global__ __launch_bounds__(256) void mix_kernel(const float* __restrict__ x,
                                                  const float* __restrict__ attn,
                                                  __hip_bfloat16* __restrict__ xmt) {
    int b = blockIdx.x >> 4;
    int hwg = blockIdx.x & 15;                  // group of 8 hw positions
    __shared__ float at[64];
    __shared__ float xs[8][8][33];              // [s][h][ci], ci-dim padded to 33
    int tid = threadIdx.x;
    if (tid < 64) at[tid] = attn[b * 64 + tid];
    int ci = tid >> 3, s = tid & 7;             // staging role: 32 c x 8 s
    int h = tid >> 5, cq = tid & 31;            // compute role: 8 h x 32 c
    const float* xb = x + ((size_t)b << 20);
    __hip_bfloat16* ob = xmt + ((size_t)b << 20);
    for (int cc = 0; cc < 32; ++cc) {
        const float4* src = (const float4*)(xb + ((size_t)(cc * 32 + ci) * 8 + s) * 128 + hwg * 8);
        float4 v0 = src[0], v1 = src[1];
        __syncthreads();
        xs[s][0][ci] = v0.x; xs[s][1][ci] = v0.y; xs[s][2][ci] = v0.z; xs[s][3][ci] = v0.w;
        xs[s][4][ci] = v1.x; xs[s][5][ci] = v1.y; xs[s][6][ci] = v1.z; xs[s][7][ci] = v1.w;
        __syncthreads();
        float xr[8];
        #pragma unroll
        for (int ss = 0; ss < 8; ss++) xr[ss] = xs[ss][h][cq];
        #pragma unroll
        for (int t = 0; t < 8; t++) {
            float o = 0.0f;
            #pragma unroll
            for (int ss = 0; ss < 8; ss++) o += at[t * 8 + ss] * xr[ss];
            ob[(size_t)(t * 128 + hwg * 8 + h) * 1024 + cc * 32 + cq] = __float2bfloat16(o);
        }
    }
}

// ---------------------------------------------------------------- fused GEMM + BN + residual
// out[b][c][n] = inv[c] * sum_k M[c][k]*xm_t[b][n][k] + shift[c] + x[b][c][n]
#if defined(__has_builtin)
#if __has_builtin(__builtin_amdgcn_global_load_lds)
#define USE_GLOAD_LDS 1
#endif
#endif

__device__ __forceinline__ void gload_lds16(const void* g, void* ldsbase) {
#ifdef USE_GLOAD_LDS
    __builtin_amdgcn_global_load_lds(
        (__attribute__((address_space(1))) void*)(g),
        (__attribute__((address_space(3))) void*)(ldsbase), 16, 0, 0);
#endif
}

__global__ __launch_bounds__(256) void gemm_kernel(
        const __hip_bfloat16* __restrict__ Mw,    // [1024][1024]  (c, k)
        const __hip_bfloat16* __restrict__ xmt,   // [32][1024][1024] (n, k)
        const float* __restrict__ x,              // [32][1024][1024] (c, n)
        const float* __restrict__ inv, const float* __restrict__ shift,
        float* __restrict__ out) {
    __shared__ __align__(16) __hip_bfloat16 As[128 * 32];
    __shared__ __align__(16) __hip_bfloat16 Bs[128 * 32];
    int bid = blockIdx.x;
    int b = bid >> 6;
    int mb = (bid >> 3) & 7;
    int nb = bid & 7;
    int c0 = mb * 128, n0 = nb * 128;
    int tid = threadIdx.x;
    int w = tid >> 6, l = tid & 63;
    int wr = w >> 1, wc = w & 1;
    const __hip_bfloat16* Ab = Mw + (size_t)c0 * 1024;
    const __hip_bfloat16* Bb = xmt + ((size_t)b << 20) + (size_t)n0 * 1024;
    int arow = tid >> 2, akq = tid & 3;       // staging: 4 lanes per 32-elem row
    f32x4 acc[4][4] = {};

    for (int kk = 0; kk < 32; ++kk) {
        int k0 = kk * 32;
#ifdef USE_GLOAD_LDS
        gload_lds16(Ab + (size_t)arow * 1024 + k0 + akq * 8,        (char*)As + w * 1024);
        gload_lds16(Ab + (size_t)(arow + 64) * 1024 + k0 + akq * 8, (char*)As + 4096 + w * 1024);
        gload_lds16(Bb + (size_t)arow * 1024 + k0 + akq * 8,        (char*)Bs + w * 1024);
        gload_lds16(Bb + (size_t)(arow + 64) * 1024 + k0 + akq * 8, (char*)Bs + 4096 + w * 1024);
#else
        *(bf16x8*)((char*)As + (size_t)tid * 16)        = *(const bf16x8*)(Ab + (size_t)arow * 1024 + k0 + akq * 8);
        *(bf16x8*)((char*)As + 4096 + (size_t)tid * 16) = *(const bf16x8*)(Ab + (size_t)(arow + 64) * 1024 + k0 + akq * 8);
        *(bf16x8*)((char*)Bs + (size_t)tid * 16)        = *(const bf16x8*)(Bb + (size_t)arow * 1024 + k0 + akq * 8);
        *(bf16x8*)((char*)Bs + 4096 + (size_t)tid * 16) = *(const bf16x8*)(Bb + (size_t)(arow + 64) * 1024 + k0 + akq * 8);
#endif
        __syncthreads();
        const __hip_bfloat16* Ap = As + ((size_t)(wr * 64 + (l & 15)) * 32) + (l >> 4) * 8;
        const __hip_bfloat16* Bp = Bs + ((size_t)(wc * 64 + (l & 15)) * 32) + (l >> 4) * 8;
        bf16x8 af[4], bfr[4];
        #pragma unroll
        for (int m = 0; m < 4; m++) af[m] = *(const bf16x8*)(Ap + m * 16 * 32);
        #pragma unroll
        for (int n = 0; n < 4; n++) bfr[n] = *(const bf16x8*)(Bp + n * 16 * 32);
        #pragma unroll
        for (int m = 0; m < 4; m++)
            #pragma unroll
            for (int n = 0; n < 4; n++)
                acc[m][n] = __builtin_amdgcn_mfma_f32_16x16x32_bf16(af[m], bfr[n], acc[m][n], 0, 0, 0);
        __syncthreads();
    }

    // epilogue: C/D layout col = l&15, row = (l>>4)*4 + j   [guide-verified m89/m91]
    int col = l & 15, rg = l >> 4;
    #pragma unroll
    for (int m = 0; m < 4; m++) {
        #pragma unroll
        for (int j = 0; j < 4; j++) {
            int gc = c0 + wr * 64 + m * 16 + rg * 4 + j;
            float iv = inv[gc], sh = shift[gc];
            size_t rowoff = ((size_t)b << 20) + (size_t)gc * 1024 + n0 + wc * 64 + col;
            #pragma unroll
            for (int n = 0; n < 4; n++) {
                size_t idx = rowoff + n * 16;
                out[idx] = acc[m][n][j] * iv + sh + x[idx];
            }
        }
    }
}

extern "C" void kernel_launch(void* const* d_in, const int* in_sizes, int n_in,
                              void* d_out, int out_size, void* d_ws, size_t ws_size,
                              hipStream_t stream) {
    const float* x    = (const float*)d_in[0];
    const float* g_w  = (const float*)d_in[1];
    const float* g_b  = (const float*)d_in[2];
    const float* th_w = (const float*)d_in[3];
    const float* th_b = (const float*)d_in[4];
    const float* ph_w = (const float*)d_in[5];
    const float* ph_b = (const float*)d_in[6];
    const float* w_w  = (const float*)d_in[7];
    const float* w_b  = (const float*)d_in[8];
    const float* gam  = (const float*)d_in[9];
    const float* bet  = (const float*)d_in[10];
    const float* mea  = (const float*)d_in[11];
    const float* var  = (const float*)d_in[12];
    float* out = (float*)d_out;
    char* ws = (char*)d_ws;

    __hip_bfloat16* xmt = (__hip_bfloat16*)ws;                    // 64 MiB
    __hip_bfloat16* Mw  = (__hip_bfloat16*)(ws + 67108864);       // 2 MiB
    float* xbar  = (float*)(ws + 69206016);                       // 1 MiB
    float* theta = (float*)(ws + 70254592);                       // 512 KiB
    float* phi   = (float*)(ws + 70778880);                       // 512 KiB
    float* attn  = (float*)(ws + 71303168);                       // 8 KiB
    float* inv   = (float*)(ws + 71311360);                       // 4 KiB
    float* shift = (float*)(ws + 71315456);                       // 4 KiB

    hipLaunchKernelGGL(pool_kernel, dim3(16384), dim3(256), 0, stream, x, xbar);
    hipLaunchKernelGGL(thetaphi_kernel, dim3(1024), dim3(256), 0, stream,
                       xbar, th_w, th_b, ph_w, ph_b, theta, phi);
    hipLaunchKernelGGL(attn_kernel, dim3(32), dim3(64), 0, stream, theta, phi, attn);
    hipLaunchKernelGGL(prepM_kernel, dim3(256), dim3(256), 0, stream, w_w, g_w, Mw);
    hipLaunchKernelGGL(prepbias_kernel, dim3(4), dim3(256), 0, stream,
                       w_w, g_b, w_b, gam, bet, mea, var, inv, shift);
    hipLaunchKernelGGL(mix_kernel, dim3(512), dim3(256), 0, stream, x, attn, xmt);
    hipLaunchKernelGGL(gemm_kernel, dim3(2048), dim3(256), 0, stream,
                       Mw, xmt, x, inv, shift, out);
}

// Round 2
// 317.710 us; speedup vs baseline: 1.6826x; 1.6826x over previous
//
#include <hip/hip_runtime.h>
#include <hip/hip_bf16.h>

typedef __attribute__((ext_vector_type(8))) short bf16x8;
typedef __attribute__((ext_vector_type(4))) float f32x4;

// ---------------------------------------------------------------- pool: xbar[b][c][t] = mean_hw x
__global__ __launch_bounds__(256) void pool_kernel(const float* __restrict__ x,
                                                   float* __restrict__ xbar) {
    int row = blockIdx.x * 16 + (threadIdx.x >> 4);   // (b*1024+c)*8+t
    int j = threadIdx.x & 15;
    const float4* p = (const float4*)(x + (size_t)row * 128);
    float4 a = p[j * 2], b2 = p[j * 2 + 1];
    float s = a.x + a.y + a.z + a.w + b2.x + b2.y + b2.z + b2.w;
    s += __shfl_xor(s, 1); s += __shfl_xor(s, 2);
    s += __shfl_xor(s, 4); s += __shfl_xor(s, 8);
    if (j == 0) xbar[row] = s * (1.0f / 128.0f);
}

// ------------------------------------------- theta/phi: [b][ic][t] = W @ xbar[b][:][t] + bias
__global__ __launch_bounds__(256) void thetaphi_kernel(
        const float* __restrict__ xbar,
        const float* __restrict__ tw, const float* __restrict__ tb,
        const float* __restrict__ pw, const float* __restrict__ pb,
        float* __restrict__ theta, float* __restrict__ phi) {
    int which = blockIdx.x & 1;
    int icc = (blockIdx.x >> 1) & 15;
    int b = blockIdx.x >> 5;
    const float* w = which ? pw : tw;
    const float* bias = which ? pb : tb;
    float* out = which ? phi : theta;
    __shared__ float xs[8192];
    for (int i = threadIdx.x; i < 8192; i += 256) xs[i] = xbar[b * 8192 + i];
    __syncthreads();
    int icl = threadIdx.x >> 3;
    int t = threadIdx.x & 7;
    int ic = icc * 32 + icl;
    const float* wr = w + (size_t)ic * 1024;
    float acc = 0.0f;
    #pragma unroll 8
    for (int k = 0; k < 1024; k++) acc += wr[k] * xs[k * 8 + t];
    out[((size_t)b * 512 + ic) * 8 + t] = acc + bias[ic];
}

// ------------------------------------------------------- attn[b][t][s] = softmax_s(theta.phi)
__global__ __launch_bounds__(64) void attn_kernel(const float* __restrict__ theta,
                                                  const float* __restrict__ phi,
                                                  float* __restrict__ attn) {
    __shared__ float th[4096], ph[4096];
    int b = blockIdx.x, lane = threadIdx.x;
    for (int i = lane; i < 4096; i += 64) {
        th[i] = theta[(size_t)b * 4096 + i];
        ph[i] = phi[(size_t)b * 4096 + i];
    }
    __syncthreads();
    int t = lane >> 3, s = lane & 7;
    float f = 0.0f;
    #pragma unroll 8
    for (int ic = 0; ic < 512; ic++) f += th[ic * 8 + t] * ph[ic * 8 + s];
    float m = f;
    m = fmaxf(m, __shfl_xor(m, 1));
    m = fmaxf(m, __shfl_xor(m, 2));
    m = fmaxf(m, __shfl_xor(m, 4));
    float e = __expf(f - m);
    float sum = e;
    sum += __shfl_xor(sum, 1); sum += __shfl_xor(sum, 2); sum += __shfl_xor(sum, 4);
    attn[b * 64 + lane] = e / sum;
}

// --------------------------- prep: gwt[cin][ic] = bf16(g_w[ic][cin]); wwb = bf16(w_w)
__global__ __launch_bounds__(256) void prep_operands_kernel(
        const float* __restrict__ gw, const float* __restrict__ ww,
        __hip_bfloat16* __restrict__ gwt, __hip_bfloat16* __restrict__ wwb) {
    int bid = blockIdx.x;
    if (bid < 512) {
        // transpose+cvt a 32(ic) x 32(cin) tile of g_w [512][1024]
        int icb = bid >> 5;            // 0..15
        int cb = bid & 31;             // 0..31
        __shared__ float tile[32][33];
        int r = threadIdx.x >> 5, c = threadIdx.x & 31;   // 8 x 32
        #pragma unroll
        for (int i = 0; i < 4; i++)
            tile[r + i * 8][c] = gw[(size_t)(icb * 32 + r + i * 8) * 1024 + cb * 32 + c];
        __syncthreads();
        #pragma unroll
        for (int i = 0; i < 4; i++) {
            int cin = cb * 32 + r + i * 8;
            gwt[(size_t)cin * 512 + icb * 32 + c] = __float2bfloat16(tile[c][r + i * 8]);
        }
    } else {
        // convert w_w (1024x512 fp32) to bf16, 2048 elems/block
        int b2 = bid - 512;
        size_t base = (size_t)b2 * 2048 + (size_t)threadIdx.x * 8;
        const float4* src = (const float4*)(ww + base);
        float4 v0 = src[0], v1 = src[1];
        __hip_bfloat16 tmp[8];
        tmp[0] = __float2bfloat16(v0.x); tmp[1] = __float2bfloat16(v0.y);
        tmp[2] = __float2bfloat16(v0.z); tmp[3] = __float2bfloat16(v0.w);
        tmp[4] = __float2bfloat16(v1.x); tmp[5] = __float2bfloat16(v1.y);
        tmp[6] = __float2bfloat16(v1.z); tmp[7] = __float2bfloat16(v1.w);
        *(bf16x8*)(wwb + base) = *(const bf16x8*)tmp;
    }
}

#if defined(__has_builtin)
#if __has_builtin(__builtin_amdgcn_global_load_lds)
#define USE_GLOAD_LDS 1
#endif
#endif

__device__ __forceinline__ void gload_lds16(const void* g, void* ldsbase) {
#ifdef USE_GLOAD_LDS
    __builtin_amdgcn_global_load_lds(
        (__attribute__((address_space(1))) void*)(g),
        (__attribute__((address_space(3))) void*)(ldsbase), 16, 0, 0);
#endif
}

// --------------------------- prepM via MFMA: M[c][cin] = sum_k wwb[c][k]*gwt[cin][k]
__global__ __launch_bounds__(256) void prepM_mfma_kernel(
        const __hip_bfloat16* __restrict__ wwb,   // [1024][512]
        const __hip_bfloat16* __restrict__ gwt,   // [1024][512]
        __hip_bfloat16* __restrict__ M) {
    __shared__ __align__(16) __hip_bfloat16 As[128 * 32];
    __shared__ __align__(16) __hip_bfloat16 Bs[128 * 32];
    int bid = blockIdx.x;
    int mb = bid >> 3, nb = bid & 7;
    int c0 = mb * 128, n0 = nb * 128;
    int tid = threadIdx.x;
    int w = tid >> 6, l = tid & 63;
    int wr = w >> 1, wc = w & 1;
    const __hip_bfloat16* Ab = wwb + (size_t)c0 * 512;
    const __hip_bfloat16* Bb = gwt + (size_t)n0 * 512;
    int arow = tid >> 2, akq = tid & 3;
    f32x4 acc[4][4] = {};

    for (int kk = 0; kk < 16; ++kk) {
        int k0 = kk * 32;
#ifdef USE_GLOAD_LDS
        gload_lds16(Ab + (size_t)arow * 512 + k0 + akq * 8,        (char*)As + w * 1024);
        gload_lds16(Ab + (size_t)(arow + 64) * 512 + k0 + akq * 8, (char*)As + 4096 + w * 1024);
        gload_lds16(Bb + (size_t)arow * 512 + k0 + akq * 8,        (char*)Bs + w * 1024);
        gload_lds16(Bb + (size_t)(arow + 64) * 512 + k0 + akq * 8, (char*)Bs + 4096 + w * 1024);
#else
        *(bf16x8*)((char*)As + (size_t)tid * 16)        = *(const bf16x8*)(Ab + (size_t)arow * 512 + k0 + akq * 8);
        *(bf16x8*)((char*)As + 4096 + (size_t)tid * 16) = *(const bf16x8*)(Ab + (size_t)(arow + 64) * 512 + k0 + akq * 8);
        *(bf16x8*)((char*)Bs + (size_t)tid * 16)        = *(const bf16x8*)(Bb + (size_t)arow * 512 + k0 + akq * 8);
        *(bf16x8*)((char*)Bs + 4096 + (size_t)tid * 16) = *(const bf16x8*)(Bb + (size_t)(arow + 64) * 512 + k0 + akq * 8);
#endif
        __syncthreads();
        const __hip_bfloat16* Ap = As + ((size_t)(wr * 64 + (l & 15)) * 32) + (l >> 4) * 8;
        const __hip_bfloat16* Bp = Bs + ((size_t)(wc * 64 + (l & 15)) * 32) + (l >> 4) * 8;
        bf16x8 af[4], bfr[4];
        #pragma unroll
        for (int m = 0; m < 4; m++) af[m] = *(const bf16x8*)(Ap + m * 16 * 32);
        #pragma unroll
        for (int n = 0; n < 4; n++) bfr[n] = *(const bf16x8*)(Bp + n * 16 * 32);
        #pragma unroll
        for (int m = 0; m < 4; m++)
            #pragma unroll
            for (int n = 0; n < 4; n++)
                acc[m][n] = __builtin_amdgcn_mfma_f32_16x16x32_bf16(af[m], bfr[n], acc[m][n], 0, 0, 0);
        __syncthreads();
    }

    int col = l & 15, rg = l >> 4;
    #pragma unroll
    for (int m = 0; m < 4; m++)
        #pragma unroll
        for (int j = 0; j < 4; j++) {
            int gc = c0 + wr * 64 + m * 16 + rg * 4 + j;
            #pragma unroll
            for (int n = 0; n < 4; n++)
                M[(size_t)gc * 1024 + n0 + wc * 64 + n * 16 + col] = __float2bfloat16(acc[m][n][j]);
        }
}

// ------------------------------------------- per-channel epilogue constants inv[c], shift[c]
__global__ __launch_bounds__(256) void prepbias_kernel(
        const float* __restrict__ ww, const float* __restrict__ gb,
        const float* __restrict__ wb, const float* __restrict__ gamma,
        const float* __restrict__ beta, const float* __restrict__ mean,
        const float* __restrict__ var, float* __restrict__ inv,
        float* __restrict__ shift) {
    int c = blockIdx.x * 256 + threadIdx.x;
    float cb = wb[c];
    const float* wr = ww + (size_t)c * 512;
    for (int k = 0; k < 512; k++) cb += wr[k] * gb[k];
    float iv = gamma[c] * rsqrtf(var[c] + 1e-5f);
    inv[c] = iv;
    shift[c] = cb * iv + beta[c] - mean[c] * iv;
}

// ------------- mix + transpose: xm_t[b][t*128+hw][c] (bf16) = sum_s attn[b][t][s]*x[b][c][s][hw]
__global__ __launch_bounds__(256) void mix_kernel(const float* __restrict__ x,
                                                  const float* __restrict__ attn,
                                                  __hip_bfloat16* __restrict__ xmt) {
    int b = blockIdx.x >> 4;
    int hwg = blockIdx.x & 15;                  // group of 8 hw positions
    __shared__ float at[64];
    __shared__ float xs[8][8][33];              // [s][h][ci], ci-dim padded to 33
    int tid = threadIdx.x;
    if (tid < 64) at[tid] = attn[b * 64 + tid];
    int ci = tid >> 3, s = tid & 7;             // staging role: 32 c x 8 s
    int h = tid >> 5, cq = tid & 31;            // compute role: 8 h x 32 c
    const float* xb = x + ((size_t)b << 20);
    __hip_bfloat16* ob = xmt + ((size_t)b << 20);
    for (int cc = 0; cc < 32; ++cc) {
        const float4* src = (const float4*)(xb + ((size_t)(cc * 32 + ci) * 8 + s) * 128 + hwg * 8);
        float4 v0 = src[0], v1 = src[1];
        __syncthreads();
        xs[s][0][ci] = v0.x; xs[s][1][ci] = v0.y; xs[s][2][ci] = v0.z; xs[s][3][ci] = v0.w;
        xs[s][4][ci] = v1.x; xs[s][5][ci] = v1.y; xs[s][6][ci] = v1.z; xs[s][7][ci] = v1.w;
        __syncthreads();
        float xr[8];
        #pragma unroll
        for (int ss = 0; ss < 8; ss++) xr[ss] = xs[ss][h][cq];
        #pragma unroll
        for (int t = 0; t < 8; t++) {
            float o = 0.0f;
            #pragma unroll
            for (int ss = 0; ss < 8; ss++) o += at[t * 8 + ss] * xr[ss];
            ob[(size_t)(t * 128 + hwg * 8 + h) * 1024 + cc * 32 + cq] = __float2bfloat16(o);
        }
    }
}

// ---------------------------------------------------------------- fused GEMM + BN + residual
// out[b][c][n] = inv[c] * sum_k M[c][k]*xm_t[b][n][k] + shift[c] + x[b][c][n]
__global__ __launch_bounds__(256) void gemm_kernel(
        const __hip_bfloat16* __restrict__ Mw,    // [1024][1024]  (c, k)
        const __hip_bfloat16* __restrict__ xmt,   // [32][1024][1024] (n, k)
        const float* __restrict__ x,              // [32][1024][1024] (c, n)
        const float* __restrict__ inv, const float* __restrict__ shift,
        float* __restrict__ out) {
    __shared__ __align__(16) __hip_bfloat16 As[128 * 32];
    __shared__ __align__(16) __hip_bfloat16 Bs[128 * 32];
    int bid = blockIdx.x;
    int b = bid >> 6;
    int mb = (bid >> 3) & 7;
    int nb = bid & 7;
    int c0 = mb * 128, n0 = nb * 128;
    int tid = threadIdx.x;
    int w = tid >> 6, l = tid & 63;
    int wr = w >> 1, wc = w & 1;
    const __hip_bfloat16* Ab = Mw + (size_t)c0 * 1024;
    const __hip_bfloat16* Bb = xmt + ((size_t)b << 20) + (size_t)n0 * 1024;
    int arow = tid >> 2, akq = tid & 3;       // staging: 4 lanes per 32-elem row
    f32x4 acc[4][4] = {};

    for (int kk = 0; kk < 32; ++kk) {
        int k0 = kk * 32;
#ifdef USE_GLOAD_LDS
        gload_lds16(Ab + (size_t)arow * 1024 + k0 + akq * 8,        (char*)As + w * 1024);
        gload_lds16(Ab + (size_t)(arow + 64) * 1024 + k0 + akq * 8, (char*)As + 4096 + w * 1024);
        gload_lds16(Bb + (size_t)arow * 1024 + k0 + akq * 8,        (char*)Bs + w * 1024);
        gload_lds16(Bb + (size_t)(arow + 64) * 1024 + k0 + akq * 8, (char*)Bs + 4096 + w * 1024);
#else
        *(bf16x8*)((char*)As + (size_t)tid * 16)        = *(const bf16x8*)(Ab + (size_t)arow * 1024 + k0 + akq * 8);
        *(bf16x8*)((char*)As + 4096 + (size_t)tid * 16) = *(const bf16x8*)(Ab + (size_t)(arow + 64) * 1024 + k0 + akq * 8);
        *(bf16x8*)((char*)Bs + (size_t)tid * 16)        = *(const bf16x8*)(Bb + (size_t)arow * 1024 + k0 + akq * 8);
        *(bf16x8*)((char*)Bs + 4096 + (size_t)tid * 16) = *(const bf16x8*)(Bb + (size_t)(arow + 64) * 1024 + k0 + akq * 8);
#endif
        __syncthreads();
        const __hip_bfloat16* Ap = As + ((size_t)(wr * 64 + (l & 15)) * 32) + (l >> 4) * 8;
        const __hip_bfloat16* Bp = Bs + ((size_t)(wc * 64 + (l & 15)) * 32) + (l >> 4) * 8;
        bf16x8 af[4], bfr[4];
        #pragma unroll
        for (int m = 0; m < 4; m++) af[m] = *(const bf16x8*)(Ap + m * 16 * 32);
        #pragma unroll
        for (int n = 0; n < 4; n++) bfr[n] = *(const bf16x8*)(Bp + n * 16 * 32);
        #pragma unroll
        for (int m = 0; m < 4; m++)
            #pragma unroll
            for (int n = 0; n < 4; n++)
                acc[m][n] = __builtin_amdgcn_mfma_f32_16x16x32_bf16(af[m], bfr[n], acc[m][n], 0, 0, 0);
        __syncthreads();
    }

    // epilogue: C/D layout col = l&15, row = (l>>4)*4 + j   [guide-verified m89/m91]
    int col = l & 15, rg = l >> 4;
    #pragma unroll
    for (int m = 0; m < 4; m++) {
        #pragma unroll
        for (int j = 0; j < 4; j++) {
            int gc = c0 + wr * 64 + m * 16 + rg * 4 + j;
            float iv = inv[gc], sh = shift[gc];
            size_t rowoff = ((size_t)b << 20) + (size_t)gc * 1024 + n0 + wc * 64 + col;
            #pragma unroll
            for (int n = 0; n < 4; n++) {
                size_t idx = rowoff + n * 16;
                out[idx] = acc[m][n][j] * iv + sh + x[idx];
            }
        }
    }
}

extern "C" void kernel_launch(void* const* d_in, const int* in_sizes, int n_in,
                              void* d_out, int out_size, void* d_ws, size_t ws_size,
                              hipStream_t stream) {
    const float* x    = (const float*)d_in[0];
    const float* g_w  = (const float*)d_in[1];
    const float* g_b  = (const float*)d_in[2];
    const float* th_w = (const float*)d_in[3];
    const float* th_b = (const float*)d_in[4];
    const float* ph_w = (const float*)d_in[5];
    const float* ph_b = (const float*)d_in[6];
    const float* w_w  = (const float*)d_in[7];
    const float* w_b  = (const float*)d_in[8];
    const float* gam  = (const float*)d_in[9];
    const float* bet  = (const float*)d_in[10];
    const float* mea  = (const float*)d_in[11];
    const float* var  = (const float*)d_in[12];
    float* out = (float*)d_out;
    char* ws = (char*)d_ws;

    __hip_bfloat16* xmt = (__hip_bfloat16*)ws;                    // 64 MiB (written by mix, late)
    __hip_bfloat16* Mw  = (__hip_bfloat16*)(ws + 67108864);       // 2 MiB
    float* xbar  = (float*)(ws + 69206016);                       // 1 MiB
    float* theta = (float*)(ws + 70254592);                       // 512 KiB
    float* phi   = (float*)(ws + 70778880);                       // 512 KiB
    float* attn  = (float*)(ws + 71303168);                       // 8 KiB
    float* inv   = (float*)(ws + 71311360);                       // 4 KiB
    float* shift = (float*)(ws + 71315456);                       // 4 KiB
    // gwt/wwb overlay the xmt region: consumed by prepM_mfma BEFORE mix writes xmt
    __hip_bfloat16* gwt = (__hip_bfloat16*)ws;                    // 1 MiB
    __hip_bfloat16* wwb = (__hip_bfloat16*)(ws + 1048576);        // 1 MiB

    hipLaunchKernelGGL(pool_kernel, dim3(16384), dim3(256), 0, stream, x, xbar);
    hipLaunchKernelGGL(thetaphi_kernel, dim3(1024), dim3(256), 0, stream,
                       xbar, th_w, th_b, ph_w, ph_b, theta, phi);
    hipLaunchKernelGGL(attn_kernel, dim3(32), dim3(64), 0, stream, theta, phi, attn);
    hipLaunchKernelGGL(prep_operands_kernel, dim3(768), dim3(256), 0, stream,
                       g_w, w_w, gwt, wwb);
    hipLaunchKernelGGL(prepM_mfma_kernel, dim3(64), dim3(256), 0, stream, wwb, gwt, Mw);
    hipLaunchKernelGGL(prepbias_kernel, dim3(4), dim3(256), 0, stream,
                       w_w, g_b, w_b, gam, bet, mea, var, inv, shift);
    hipLaunchKernelGGL(mix_kernel, dim3(512), dim3(256), 0, stream, x, attn, xmt);
    hipLaunchKernelGGL(gemm_kernel, dim3(2048), dim3(256), 0, stream,
                       Mw, xmt, x, inv, shift, out);
}

// Round 3
// 289.964 us; speedup vs baseline: 1.8436x; 1.0957x over previous
//
#include <hip/hip_runtime.h>
#include <hip/hip_bf16.h>

typedef __attribute__((ext_vector_type(8))) short bf16x8;
typedef __attribute__((ext_vector_type(4))) float f32x4;

// ---------------------------------------------------------------- pool: xbar[b][c][t] = mean_hw x
__global__ __launch_bounds__(256) void pool_kernel(const float* __restrict__ x,
                                                   float* __restrict__ xbar) {
    int row = blockIdx.x * 16 + (threadIdx.x >> 4);   // (b*1024+c)*8+t
    int j = threadIdx.x & 15;
    const float4* p = (const float4*)(x + (size_t)row * 128);
    float4 a = p[j * 2], b2 = p[j * 2 + 1];
    float s = a.x + a.y + a.z + a.w + b2.x + b2.y + b2.z + b2.w;
    s += __shfl_xor(s, 1); s += __shfl_xor(s, 2);
    s += __shfl_xor(s, 4); s += __shfl_xor(s, 8);
    if (j == 0) xbar[row] = s * (1.0f / 128.0f);
}

// ------------------------------------------- theta/phi: [b][ic][t] = W @ xbar[b][:][t] + bias
__global__ __launch_bounds__(256) void thetaphi_kernel(
        const float* __restrict__ xbar,
        const float* __restrict__ tw, const float* __restrict__ tb,
        const float* __restrict__ pw, const float* __restrict__ pb,
        float* __restrict__ theta, float* __restrict__ phi) {
    int which = blockIdx.x & 1;
    int icc = (blockIdx.x >> 1) & 15;
    int b = blockIdx.x >> 5;
    const float* w = which ? pw : tw;
    const float* bias = which ? pb : tb;
    float* out = which ? phi : theta;
    __shared__ float xs[8192];
    for (int i = threadIdx.x; i < 8192; i += 256) xs[i] = xbar[b * 8192 + i];
    __syncthreads();
    int icl = threadIdx.x >> 3;
    int t = threadIdx.x & 7;
    int ic = icc * 32 + icl;
    const float* wr = w + (size_t)ic * 1024;
    float acc = 0.0f;
    #pragma unroll 8
    for (int k = 0; k < 1024; k++) acc += wr[k] * xs[k * 8 + t];
    out[((size_t)b * 512 + ic) * 8 + t] = acc + bias[ic];
}

// ------------------------------------------------------- attn[b][t][s] = softmax_s(theta.phi)
__global__ __launch_bounds__(64) void attn_kernel(const float* __restrict__ theta,
                                                  const float* __restrict__ phi,
                                                  float* __restrict__ attn) {
    __shared__ float th[4096], ph[4096];
    int b = blockIdx.x, lane = threadIdx.x;
    for (int i = lane; i < 4096; i += 64) {
        th[i] = theta[(size_t)b * 4096 + i];
        ph[i] = phi[(size_t)b * 4096 + i];
    }
    __syncthreads();
    int t = lane >> 3, s = lane & 7;
    float f = 0.0f;
    #pragma unroll 8
    for (int ic = 0; ic < 512; ic++) f += th[ic * 8 + t] * ph[ic * 8 + s];
    float m = f;
    m = fmaxf(m, __shfl_xor(m, 1));
    m = fmaxf(m, __shfl_xor(m, 2));
    m = fmaxf(m, __shfl_xor(m, 4));
    float e = __expf(f - m);
    float sum = e;
    sum += __shfl_xor(sum, 1); sum += __shfl_xor(sum, 2); sum += __shfl_xor(sum, 4);
    attn[b * 64 + lane] = e / sum;
}

// --------------------------- prep: gwt[cin][ic] = bf16(g_w[ic][cin]); wwb = bf16(w_w)
__global__ __launch_bounds__(256) void prep_operands_kernel(
        const float* __restrict__ gw, const float* __restrict__ ww,
        __hip_bfloat16* __restrict__ gwt, __hip_bfloat16* __restrict__ wwb) {
    int bid = blockIdx.x;
    if (bid < 512) {
        int icb = bid >> 5;            // 0..15
        int cb = bid & 31;             // 0..31
        __shared__ float tile[32][33];
        int r = threadIdx.x >> 5, c = threadIdx.x & 31;   // 8 x 32
        #pragma unroll
        for (int i = 0; i < 4; i++)
            tile[r + i * 8][c] = gw[(size_t)(icb * 32 + r + i * 8) * 1024 + cb * 32 + c];
        __syncthreads();
        #pragma unroll
        for (int i = 0; i < 4; i++) {
            int cin = cb * 32 + r + i * 8;
            gwt[(size_t)cin * 512 + icb * 32 + c] = __float2bfloat16(tile[c][r + i * 8]);
        }
    } else {
        int b2 = bid - 512;
        size_t base = (size_t)b2 * 2048 + (size_t)threadIdx.x * 8;
        const float4* src = (const float4*)(ww + base);
        float4 v0 = src[0], v1 = src[1];
        __hip_bfloat16 tmp[8];
        tmp[0] = __float2bfloat16(v0.x); tmp[1] = __float2bfloat16(v0.y);
        tmp[2] = __float2bfloat16(v0.z); tmp[3] = __float2bfloat16(v0.w);
        tmp[4] = __float2bfloat16(v1.x); tmp[5] = __float2bfloat16(v1.y);
        tmp[6] = __float2bfloat16(v1.z); tmp[7] = __float2bfloat16(v1.w);
        *(bf16x8*)(wwb + base) = *(const bf16x8*)tmp;
    }
}

#if defined(__has_builtin)
#if __has_builtin(__builtin_amdgcn_global_load_lds)
#define USE_GLOAD_LDS 1
#endif
#endif

__device__ __forceinline__ void gload_lds16(const void* g, void* ldsbase) {
#ifdef USE_GLOAD_LDS
    __builtin_amdgcn_global_load_lds(
        (__attribute__((address_space(1))) void*)(g),
        (__attribute__((address_space(3))) void*)(ldsbase), 16, 0, 0);
#endif
}

// --------------------------- prepM via MFMA: M[c][cin] = sum_k wwb[c][k]*gwt[cin][k]
__global__ __launch_bounds__(256) void prepM_mfma_kernel(
        const __hip_bfloat16* __restrict__ wwb,   // [1024][512]
        const __hip_bfloat16* __restrict__ gwt,   // [1024][512]
        __hip_bfloat16* __restrict__ M) {
    __shared__ __align__(16) __hip_bfloat16 As[128 * 32];
    __shared__ __align__(16) __hip_bfloat16 Bs[128 * 32];
    int bid = blockIdx.x;
    int mb = bid >> 3, nb = bid & 7;
    int c0 = mb * 128, n0 = nb * 128;
    int tid = threadIdx.x;
    int w = tid >> 6, l = tid & 63;
    int wr = w >> 1, wc = w & 1;
    const __hip_bfloat16* Ab = wwb + (size_t)c0 * 512;
    const __hip_bfloat16* Bb = gwt + (size_t)n0 * 512;
    int arow = tid >> 2, akq = tid & 3;
    f32x4 acc[4][4] = {};

    for (int kk = 0; kk < 16; ++kk) {
        int k0 = kk * 32;
#ifdef USE_GLOAD_LDS
        gload_lds16(Ab + (size_t)arow * 512 + k0 + akq * 8,        (char*)As + w * 1024);
        gload_lds16(Ab + (size_t)(arow + 64) * 512 + k0 + akq * 8, (char*)As + 4096 + w * 1024);
        gload_lds16(Bb + (size_t)arow * 512 + k0 + akq * 8,        (char*)Bs + w * 1024);
        gload_lds16(Bb + (size_t)(arow + 64) * 512 + k0 + akq * 8, (char*)Bs + 4096 + w * 1024);
#else
        *(bf16x8*)((char*)As + (size_t)tid * 16)        = *(const bf16x8*)(Ab + (size_t)arow * 512 + k0 + akq * 8);
        *(bf16x8*)((char*)As + 4096 + (size_t)tid * 16) = *(const bf16x8*)(Ab + (size_t)(arow + 64) * 512 + k0 + akq * 8);
        *(bf16x8*)((char*)Bs + (size_t)tid * 16)        = *(const bf16x8*)(Bb + (size_t)arow * 512 + k0 + akq * 8);
        *(bf16x8*)((char*)Bs + 4096 + (size_t)tid * 16) = *(const bf16x8*)(Bb + (size_t)(arow + 64) * 512 + k0 + akq * 8);
#endif
        __syncthreads();
        const __hip_bfloat16* Ap = As + ((size_t)(wr * 64 + (l & 15)) * 32) + (l >> 4) * 8;
        const __hip_bfloat16* Bp = Bs + ((size_t)(wc * 64 + (l & 15)) * 32) + (l >> 4) * 8;
        bf16x8 af[4], bfr[4];
        #pragma unroll
        for (int m = 0; m < 4; m++) af[m] = *(const bf16x8*)(Ap + m * 16 * 32);
        #pragma unroll
        for (int n = 0; n < 4; n++) bfr[n] = *(const bf16x8*)(Bp + n * 16 * 32);
        #pragma unroll
        for (int m = 0; m < 4; m++)
            #pragma unroll
            for (int n = 0; n < 4; n++)
                acc[m][n] = __builtin_amdgcn_mfma_f32_16x16x32_bf16(af[m], bfr[n], acc[m][n], 0, 0, 0);
        __syncthreads();
    }

    int col = l & 15, rg = l >> 4;
    #pragma unroll
    for (int m = 0; m < 4; m++)
        #pragma unroll
        for (int j = 0; j < 4; j++) {
            int gc = c0 + wr * 64 + m * 16 + rg * 4 + j;
            #pragma unroll
            for (int n = 0; n < 4; n++)
                M[(size_t)gc * 1024 + n0 + wc * 64 + n * 16 + col] = __float2bfloat16(acc[m][n][j]);
        }
}

// ---------------- per-channel epilogue constants inv[c], shift[c] (wave-parallel dot)
__global__ __launch_bounds__(256) void prepbias_kernel(
        const float* __restrict__ ww, const float* __restrict__ gb,
        const float* __restrict__ wb, const float* __restrict__ gamma,
        const float* __restrict__ beta, const float* __restrict__ mean,
        const float* __restrict__ var, float* __restrict__ inv,
        float* __restrict__ shift) {
    int wv = threadIdx.x >> 6, l = threadIdx.x & 63;
    int c = blockIdx.x * 32 + wv * 8 + (l >> 3);   // 32 blocks x 32 channels
    int j = l & 7;
    const float* wr = ww + (size_t)c * 512;
    float acc = 0.0f;
    #pragma unroll 8
    for (int k = j; k < 512; k += 8) acc += wr[k] * gb[k];
    acc += __shfl_xor(acc, 1); acc += __shfl_xor(acc, 2); acc += __shfl_xor(acc, 4);
    if (j == 0) {
        float cb = wb[c] + acc;
        float iv = gamma[c] * rsqrtf(var[c] + 1e-5f);
        inv[c] = iv;
        shift[c] = cb * iv + beta[c] - mean[c] * iv;
    }
}

// ------------- mix + transpose: xm_t[b][t*128+hw][c] (bf16) = sum_s attn[b][t][s]*x[b][c][s][hw]
__global__ __launch_bounds__(256) void mix_kernel(const float* __restrict__ x,
                                                  const float* __restrict__ attn,
                                                  __hip_bfloat16* __restrict__ xmt) {
    // XCD-chunked swizzle: 512 blocks, 64 per XCD -> the 16 hwg-blocks of each b
    // share one XCD's L2 (each reads disjoint 32B of the same 512B rows).
    int orig = blockIdx.x;
    int wg = (orig & 7) * 64 + (orig >> 3);
    int b = wg >> 4;
    int hwg = wg & 15;                          // group of 8 hw positions
    __shared__ float at[64];
    __shared__ float xs[8][8][33];              // [s][h][ci], ci-dim padded to 33
    int tid = threadIdx.x;
    if (tid < 64) at[tid] = attn[b * 64 + tid];
    int ci = tid >> 3, s = tid & 7;             // staging role: 32 c x 8 s
    int h = tid >> 5, cq = tid & 31;            // compute role: 8 h x 32 c
    const float* xb = x + ((size_t)b << 20);
    __hip_bfloat16* ob = xmt + ((size_t)b << 20);
    for (int cc = 0; cc < 32; ++cc) {
        const float4* src = (const float4*)(xb + ((size_t)(cc * 32 + ci) * 8 + s) * 128 + hwg * 8);
        float4 v0 = src[0], v1 = src[1];
        __syncthreads();
        xs[s][0][ci] = v0.x; xs[s][1][ci] = v0.y; xs[s][2][ci] = v0.z; xs[s][3][ci] = v0.w;
        xs[s][4][ci] = v1.x; xs[s][5][ci] = v1.y; xs[s][6][ci] = v1.z; xs[s][7][ci] = v1.w;
        __syncthreads();
        float xr[8];
        #pragma unroll
        for (int ss = 0; ss < 8; ss++) xr[ss] = xs[ss][h][cq];
        #pragma unroll
        for (int t = 0; t < 8; t++) {
            float o = 0.0f;
            #pragma unroll
            for (int ss = 0; ss < 8; ss++) o += at[t * 8 + ss] * xr[ss];
            ob[(size_t)(t * 128 + hwg * 8 + h) * 1024 + cc * 32 + cq] = __float2bfloat16(o);
        }
    }
}

// ---------------------------------------------------------------- fused GEMM + BN + residual
// out[b][c][n] = inv[c] * sum_k M[c][k]*xm_t[b][n][k] + shift[c] + x[b][c][n]
// 2-phase prefetch: STAGE(next) issued before ds_read+MFMA(cur); ONE barrier per K-step.
__global__ __launch_bounds__(256) void gemm_kernel(
        const __hip_bfloat16* __restrict__ Mw,    // [1024][1024]  (c, k)
        const __hip_bfloat16* __restrict__ xmt,   // [32][1024][1024] (n, k)
        const float* __restrict__ x,              // [32][1024][1024] (c, n)
        const float* __restrict__ inv, const float* __restrict__ shift,
        float* __restrict__ out) {
    __shared__ __align__(16) __hip_bfloat16 As[2][128 * 32];
    __shared__ __align__(16) __hip_bfloat16 Bs[2][128 * 32];
    int orig = blockIdx.x;
    int bid = (orig & 7) * 256 + (orig >> 3);     // XCD-chunked swizzle (2048 % 8 == 0)
    int b = bid >> 6;
    int mb = (bid >> 3) & 7;
    int nb = bid & 7;
    int c0 = mb * 128, n0 = nb * 128;
    int tid = threadIdx.x;
    int w = tid >> 6, l = tid & 63;
    int wr = w >> 1, wc = w & 1;
    const __hip_bfloat16* Ab = Mw + (size_t)c0 * 1024;
    const __hip_bfloat16* Bb = xmt + ((size_t)b << 20) + (size_t)n0 * 1024;
    int arow = tid >> 2, akq = tid & 3;           // staging: 4 lanes per 32-elem row

    #define STAGE(buf, kk) do { int k0_ = (kk) * 32;                                          \
        gload_lds16(Ab + (size_t)arow * 1024 + k0_ + akq * 8,        (char*)As[buf] + w * 1024);        \
        gload_lds16(Ab + (size_t)(arow + 64) * 1024 + k0_ + akq * 8, (char*)As[buf] + 4096 + w * 1024); \
        gload_lds16(Bb + (size_t)arow * 1024 + k0_ + akq * 8,        (char*)Bs[buf] + w * 1024);        \
        gload_lds16(Bb + (size_t)(arow + 64) * 1024 + k0_ + akq * 8, (char*)Bs[buf] + 4096 + w * 1024); \
    } while (0)

    f32x4 acc[4][4] = {};
    STAGE(0, 0);
    __syncthreads();                               // drains vmcnt(0) per compiler semantics
    int cur = 0;
    for (int kk = 0; kk < 32; ++kk) {
        if (kk < 31) STAGE(cur ^ 1, kk + 1);       // prefetch next K-step (overlaps compute)
        const __hip_bfloat16* Ap = As[cur] + ((size_t)(wr * 64 + (l & 15)) * 32) + (l >> 4) * 8;
        const __hip_bfloat16* Bp = Bs[cur] + ((size_t)(wc * 64 + (l & 15)) * 32) + (l >> 4) * 8;
        bf16x8 af[4], bfr[4];
        #pragma unroll
        for (int m = 0; m < 4; m++) af[m] = *(const bf16x8*)(Ap + m * 16 * 32);
        #pragma unroll
        for (int n = 0; n < 4; n++) bfr[n] = *(const bf16x8*)(Bp + n * 16 * 32);
        #pragma unroll
        for (int m = 0; m < 4; m++)
            #pragma unroll
            for (int n = 0; n < 4; n++)
                acc[m][n] = __builtin_amdgcn_mfma_f32_16x16x32_bf16(af[m], bfr[n], acc[m][n], 0, 0, 0);
        __syncthreads();                           // single barrier per K-step
        cur ^= 1;
    }
    #undef STAGE

    // epilogue: C/D layout col = l&15, row = (l>>4)*4 + j   [guide-verified m89/m91]
    int col = l & 15, rg = l >> 4;
    #pragma unroll
    for (int m = 0; m < 4; m++) {
        #pragma unroll
        for (int j = 0; j < 4; j++) {
            int gc = c0 + wr * 64 + m * 16 + rg * 4 + j;
            float iv = inv[gc], sh = shift[gc];
            size_t rowoff = ((size_t)b << 20) + (size_t)gc * 1024 + n0 + wc * 64 + col;
            #pragma unroll
            for (int n = 0; n < 4; n++) {
                size_t idx = rowoff + n * 16;
                out[idx] = acc[m][n][j] * iv + sh + x[idx];
            }
        }
    }
}

extern "C" void kernel_launch(void* const* d_in, const int* in_sizes, int n_in,
                              void* d_out, int out_size, void* d_ws, size_t ws_size,
                              hipStream_t stream) {
    const float* x    = (const float*)d_in[0];
    const float* g_w  = (const float*)d_in[1];
    const float* g_b  = (const float*)d_in[2];
    const float* th_w = (const float*)d_in[3];
    const float* th_b = (const float*)d_in[4];
    const float* ph_w = (const float*)d_in[5];
    const float* ph_b = (const float*)d_in[6];
    const float* w_w  = (const float*)d_in[7];
    const float* w_b  = (const float*)d_in[8];
    const float* gam  = (const float*)d_in[9];
    const float* bet  = (const float*)d_in[10];
    const float* mea  = (const float*)d_in[11];
    const float* var  = (const float*)d_in[12];
    float* out = (float*)d_out;
    char* ws = (char*)d_ws;

    __hip_bfloat16* xmt = (__hip_bfloat16*)ws;                    // 64 MiB (written by mix, late)
    __hip_bfloat16* Mw  = (__hip_bfloat16*)(ws + 67108864);       // 2 MiB
    float* xbar  = (float*)(ws + 69206016);                       // 1 MiB
    float* theta = (float*)(ws + 70254592);                       // 512 KiB
    float* phi   = (float*)(ws + 70778880);                       // 512 KiB
    float* attn  = (float*)(ws + 71303168);                       // 8 KiB
    float* inv   = (float*)(ws + 71311360);                       // 4 KiB
    float* shift = (float*)(ws + 71315456);                       // 4 KiB
    // gwt/wwb overlay the xmt region: consumed by prepM_mfma BEFORE mix writes xmt
    __hip_bfloat16* gwt = (__hip_bfloat16*)ws;                    // 1 MiB
    __hip_bfloat16* wwb = (__hip_bfloat16*)(ws + 1048576);        // 1 MiB

    hipLaunchKernelGGL(pool_kernel, dim3(16384), dim3(256), 0, stream, x, xbar);
    hipLaunchKernelGGL(thetaphi_kernel, dim3(1024), dim3(256), 0, stream,
                       xbar, th_w, th_b, ph_w, ph_b, theta, phi);
    hipLaunchKernelGGL(attn_kernel, dim3(32), dim3(64), 0, stream, theta, phi, attn);
    hipLaunchKernelGGL(prep_operands_kernel, dim3(768), dim3(256), 0, stream,
                       g_w, w_w, gwt, wwb);
    hipLaunchKernelGGL(prepM_mfma_kernel, dim3(64), dim3(256), 0, stream, wwb, gwt, Mw);
    hipLaunchKernelGGL(prepbias_kernel, dim3(32), dim3(256), 0, stream,
                       w_w, g_b, w_b, gam, bet, mea, var, inv, shift);
    hipLaunchKernelGGL(mix_kernel, dim3(512), dim3(256), 0, stream, x, attn, xmt);
    hipLaunchKernelGGL(gemm_kernel, dim3(2048), dim3(256), 0, stream,
                       Mw, xmt, x, inv, shift, out);
}

// Round 4
// 248.762 us; speedup vs baseline: 2.1490x; 1.1656x over previous
//
#include <hip/hip_runtime.h>
#include <hip/hip_bf16.h>

typedef __attribute__((ext_vector_type(8))) short bf16x8;
typedef __attribute__((ext_vector_type(4))) float f32x4;

// ---------------------------------------------------------------- pool: xbar[b][c][t] = mean_hw x
__global__ __launch_bounds__(256) void pool_kernel(const float* __restrict__ x,
                                                   float* __restrict__ xbar) {
    int row = blockIdx.x * 16 + (threadIdx.x >> 4);   // (b*1024+c)*8+t
    int j = threadIdx.x & 15;
    const float4* p = (const float4*)(x + (size_t)row * 128);
    float4 a = p[j * 2], b2 = p[j * 2 + 1];
    float s = a.x + a.y + a.z + a.w + b2.x + b2.y + b2.z + b2.w;
    s += __shfl_xor(s, 1); s += __shfl_xor(s, 2);
    s += __shfl_xor(s, 4); s += __shfl_xor(s, 8);
    if (j == 0) xbar[row] = s * (1.0f / 128.0f);
}

// ------------------------------------------- theta/phi: [b][ic][t] = W @ xbar[b][:][t] + bias
__global__ __launch_bounds__(256) void thetaphi_kernel(
        const float* __restrict__ xbar,
        const float* __restrict__ tw, const float* __restrict__ tb,
        const float* __restrict__ pw, const float* __restrict__ pb,
        float* __restrict__ theta, float* __restrict__ phi) {
    int which = blockIdx.x & 1;
    int icc = (blockIdx.x >> 1) & 15;
    int b = blockIdx.x >> 5;
    const float* w = which ? pw : tw;
    const float* bias = which ? pb : tb;
    float* out = which ? phi : theta;
    __shared__ float xs[8192];
    for (int i = threadIdx.x; i < 8192; i += 256) xs[i] = xbar[b * 8192 + i];
    __syncthreads();
    int icl = threadIdx.x >> 3;
    int t = threadIdx.x & 7;
    int ic = icc * 32 + icl;
    const float* wr = w + (size_t)ic * 1024;
    float acc = 0.0f;
    #pragma unroll 8
    for (int k = 0; k < 1024; k++) acc += wr[k] * xs[k * 8 + t];
    out[((size_t)b * 512 + ic) * 8 + t] = acc + bias[ic];
}

// ------------------------------------------------------- attn[b][t][s] = softmax_s(theta.phi)
__global__ __launch_bounds__(64) void attn_kernel(const float* __restrict__ theta,
                                                  const float* __restrict__ phi,
                                                  float* __restrict__ attn) {
    __shared__ float th[4096], ph[4096];
    int b = blockIdx.x, lane = threadIdx.x;
    for (int i = lane; i < 4096; i += 64) {
        th[i] = theta[(size_t)b * 4096 + i];
        ph[i] = phi[(size_t)b * 4096 + i];
    }
    __syncthreads();
    int t = lane >> 3, s = lane & 7;
    float f = 0.0f;
    #pragma unroll 8
    for (int ic = 0; ic < 512; ic++) f += th[ic * 8 + t] * ph[ic * 8 + s];
    float m = f;
    m = fmaxf(m, __shfl_xor(m, 1));
    m = fmaxf(m, __shfl_xor(m, 2));
    m = fmaxf(m, __shfl_xor(m, 4));
    float e = __expf(f - m);
    float sum = e;
    sum += __shfl_xor(sum, 1); sum += __shfl_xor(sum, 2); sum += __shfl_xor(sum, 4);
    attn[b * 64 + lane] = e / sum;
}

// --------------------------- prep: gwt[cin][ic] = bf16(g_w[ic][cin]); wwb = bf16(w_w)
__global__ __launch_bounds__(256) void prep_operands_kernel(
        const float* __restrict__ gw, const float* __restrict__ ww,
        __hip_bfloat16* __restrict__ gwt, __hip_bfloat16* __restrict__ wwb) {
    int bid = blockIdx.x;
    if (bid < 512) {
        int icb = bid >> 5;            // 0..15
        int cb = bid & 31;             // 0..31
        __shared__ float tile[32][33];
        int r = threadIdx.x >> 5, c = threadIdx.x & 31;   // 8 x 32
        #pragma unroll
        for (int i = 0; i < 4; i++)
            tile[r + i * 8][c] = gw[(size_t)(icb * 32 + r + i * 8) * 1024 + cb * 32 + c];
        __syncthreads();
        #pragma unroll
        for (int i = 0; i < 4; i++) {
            int cin = cb * 32 + r + i * 8;
            gwt[(size_t)cin * 512 + icb * 32 + c] = __float2bfloat16(tile[c][r + i * 8]);
        }
    } else {
        int b2 = bid - 512;
        size_t base = (size_t)b2 * 2048 + (size_t)threadIdx.x * 8;
        const float4* src = (const float4*)(ww + base);
        float4 v0 = src[0], v1 = src[1];
        __hip_bfloat16 tmp[8];
        tmp[0] = __float2bfloat16(v0.x); tmp[1] = __float2bfloat16(v0.y);
        tmp[2] = __float2bfloat16(v0.z); tmp[3] = __float2bfloat16(v0.w);
        tmp[4] = __float2bfloat16(v1.x); tmp[5] = __float2bfloat16(v1.y);
        tmp[6] = __float2bfloat16(v1.z); tmp[7] = __float2bfloat16(v1.w);
        *(bf16x8*)(wwb + base) = *(const bf16x8*)tmp;
    }
}

#if defined(__has_builtin)
#if __has_builtin(__builtin_amdgcn_global_load_lds)
#define USE_GLOAD_LDS 1
#endif
#endif

__device__ __forceinline__ void gload_lds16(const void* g, void* ldsbase) {
#ifdef USE_GLOAD_LDS
    __builtin_amdgcn_global_load_lds(
        (__attribute__((address_space(1))) void*)(g),
        (__attribute__((address_space(3))) void*)(ldsbase), 16, 0, 0);
#endif
}

// --------------------------- prepM via MFMA: M[c][cin] = sum_k wwb[c][k]*gwt[cin][k]
__global__ __launch_bounds__(256) void prepM_mfma_kernel(
        const __hip_bfloat16* __restrict__ wwb,   // [1024][512]
        const __hip_bfloat16* __restrict__ gwt,   // [1024][512]
        __hip_bfloat16* __restrict__ M) {
    __shared__ __align__(16) __hip_bfloat16 As[128 * 32];
    __shared__ __align__(16) __hip_bfloat16 Bs[128 * 32];
    int bid = blockIdx.x;
    int mb = bid >> 3, nb = bid & 7;
    int c0 = mb * 128, n0 = nb * 128;
    int tid = threadIdx.x;
    int w = tid >> 6, l = tid & 63;
    int wr = w >> 1, wc = w & 1;
    const __hip_bfloat16* Ab = wwb + (size_t)c0 * 512;
    const __hip_bfloat16* Bb = gwt + (size_t)n0 * 512;
    int arow = tid >> 2, akq = tid & 3;
    f32x4 acc[4][4] = {};

    for (int kk = 0; kk < 16; ++kk) {
        int k0 = kk * 32;
#ifdef USE_GLOAD_LDS
        gload_lds16(Ab + (size_t)arow * 512 + k0 + akq * 8,        (char*)As + w * 1024);
        gload_lds16(Ab + (size_t)(arow + 64) * 512 + k0 + akq * 8, (char*)As + 4096 + w * 1024);
        gload_lds16(Bb + (size_t)arow * 512 + k0 + akq * 8,        (char*)Bs + w * 1024);
        gload_lds16(Bb + (size_t)(arow + 64) * 512 + k0 + akq * 8, (char*)Bs + 4096 + w * 1024);
#else
        *(bf16x8*)((char*)As + (size_t)tid * 16)        = *(const bf16x8*)(Ab + (size_t)arow * 512 + k0 + akq * 8);
        *(bf16x8*)((char*)As + 4096 + (size_t)tid * 16) = *(const bf16x8*)(Ab + (size_t)(arow + 64) * 512 + k0 + akq * 8);
        *(bf16x8*)((char*)Bs + (size_t)tid * 16)        = *(const bf16x8*)(Bb + (size_t)arow * 512 + k0 + akq * 8);
        *(bf16x8*)((char*)Bs + 4096 + (size_t)tid * 16) = *(const bf16x8*)(Bb + (size_t)(arow + 64) * 512 + k0 + akq * 8);
#endif
        __syncthreads();
        const __hip_bfloat16* Ap = As + ((size_t)(wr * 64 + (l & 15)) * 32) + (l >> 4) * 8;
        const __hip_bfloat16* Bp = Bs + ((size_t)(wc * 64 + (l & 15)) * 32) + (l >> 4) * 8;
        bf16x8 af[4], bfr[4];
        #pragma unroll
        for (int m = 0; m < 4; m++) af[m] = *(const bf16x8*)(Ap + m * 16 * 32);
        #pragma unroll
        for (int n = 0; n < 4; n++) bfr[n] = *(const bf16x8*)(Bp + n * 16 * 32);
        #pragma unroll
        for (int m = 0; m < 4; m++)
            #pragma unroll
            for (int n = 0; n < 4; n++)
                acc[m][n] = __builtin_amdgcn_mfma_f32_16x16x32_bf16(af[m], bfr[n], acc[m][n], 0, 0, 0);
        __syncthreads();
    }

    int col = l & 15, rg = l >> 4;
    #pragma unroll
    for (int m = 0; m < 4; m++)
        #pragma unroll
        for (int j = 0; j < 4; j++) {
            int gc = c0 + wr * 64 + m * 16 + rg * 4 + j;
            #pragma unroll
            for (int n = 0; n < 4; n++)
                M[(size_t)gc * 1024 + n0 + wc * 64 + n * 16 + col] = __float2bfloat16(acc[m][n][j]);
        }
}

// ---------------- per-channel epilogue constants inv[c], shift[c] (wave-parallel dot)
__global__ __launch_bounds__(256) void prepbias_kernel(
        const float* __restrict__ ww, const float* __restrict__ gb,
        const float* __restrict__ wb, const float* __restrict__ gamma,
        const float* __restrict__ beta, const float* __restrict__ mean,
        const float* __restrict__ var, float* __restrict__ inv,
        float* __restrict__ shift) {
    int wv = threadIdx.x >> 6, l = threadIdx.x & 63;
    int c = blockIdx.x * 32 + wv * 8 + (l >> 3);   // 32 blocks x 32 channels
    int j = l & 7;
    const float* wr = ww + (size_t)c * 512;
    float acc = 0.0f;
    #pragma unroll 8
    for (int k = j; k < 512; k += 8) acc += wr[k] * gb[k];
    acc += __shfl_xor(acc, 1); acc += __shfl_xor(acc, 2); acc += __shfl_xor(acc, 4);
    if (j == 0) {
        float cb = wb[c] + acc;
        float iv = gamma[c] * rsqrtf(var[c] + 1e-5f);
        inv[c] = iv;
        shift[c] = cb * iv + beta[c] - mean[c] * iv;
    }
}

// ------------- mix + transpose: xm_t[b][t*128+hw][c] (bf16) = sum_s attn[b][t][s]*x[b][c][s][hw]
__global__ __launch_bounds__(256) void mix_kernel(const float* __restrict__ x,
                                                  const float* __restrict__ attn,
                                                  __hip_bfloat16* __restrict__ xmt) {
    int orig = blockIdx.x;
    int wg = (orig & 7) * 64 + (orig >> 3);
    int b = wg >> 4;
    int hwg = wg & 15;                          // group of 8 hw positions
    __shared__ float at[64];
    __shared__ float xs[8][8][33];              // [s][h][ci], ci-dim padded to 33
    int tid = threadIdx.x;
    if (tid < 64) at[tid] = attn[b * 64 + tid];
    int ci = tid >> 3, s = tid & 7;             // staging role: 32 c x 8 s
    int h = tid >> 5, cq = tid & 31;            // compute role: 8 h x 32 c
    const float* xb = x + ((size_t)b << 20);
    __hip_bfloat16* ob = xmt + ((size_t)b << 20);
    for (int cc = 0; cc < 32; ++cc) {
        const float4* src = (const float4*)(xb + ((size_t)(cc * 32 + ci) * 8 + s) * 128 + hwg * 8);
        float4 v0 = src[0], v1 = src[1];
        __syncthreads();
        xs[s][0][ci] = v0.x; xs[s][1][ci] = v0.y; xs[s][2][ci] = v0.z; xs[s][3][ci] = v0.w;
        xs[s][4][ci] = v1.x; xs[s][5][ci] = v1.y; xs[s][6][ci] = v1.z; xs[s][7][ci] = v1.w;
        __syncthreads();
        float xr[8];
        #pragma unroll
        for (int ss = 0; ss < 8; ss++) xr[ss] = xs[ss][h][cq];
        #pragma unroll
        for (int t = 0; t < 8; t++) {
            float o = 0.0f;
            #pragma unroll
            for (int ss = 0; ss < 8; ss++) o += at[t * 8 + ss] * xr[ss];
            ob[(size_t)(t * 128 + hwg * 8 + h) * 1024 + cc * 32 + cq] = __float2bfloat16(o);
        }
    }
}

// ================= 256x256-tile / BK=64 / 8-wave phase-scheduled GEMM + BN + residual ========
// out[b][c][n] = inv[c] * sum_k M[c][k]*xmt[b][n][k] + shift[c] + x[b][c][n]
// LDS: 2 buffers x (A 256x64 + B 256x64) bf16 = 128 KiB, XOR-swizzled (cb ^ ((row&7)<<4)),
// realized as linear LDS writes + pre-swizzled GLOBAL source (rule #21).
// Per K-tile: 4 phases {8 ds_read_b128, 2 global_load_lds (next tile), 16 MFMA w/ setprio};
// one raw s_barrier + vmcnt(0) per K-tile (loads overlap a full tile of compute).
__global__ __launch_bounds__(512, 2) void gemm256_kernel(
        const __hip_bfloat16* __restrict__ Mw,    // [1024][1024]  (c, k)
        const __hip_bfloat16* __restrict__ xmt,   // [32][1024][1024] (n, k)
        const float* __restrict__ x,              // [32][1024][1024] (c, n)
        const float* __restrict__ inv, const float* __restrict__ shift,
        float* __restrict__ out) {
    __shared__ __align__(16) __hip_bfloat16 As[2][256 * 64];   // 64 KiB
    __shared__ __align__(16) __hip_bfloat16 Bs[2][256 * 64];   // 64 KiB
    const int TSZ = 256 * 64 * 2;                              // bytes per buffer

    int orig = blockIdx.x;
    int bid = (orig & 7) * 64 + (orig >> 3);      // XCD-chunked swizzle (512 % 8 == 0)
    int b = bid >> 4;
    int mb = (bid >> 2) & 3;
    int nb = bid & 3;
    int c0 = mb * 256, n0 = nb * 256;

    int tid = threadIdx.x;
    int w = tid >> 6, l = tid & 63;
    int wr = w >> 2, wc = w & 3;                  // 2 x 4 wave grid; wave out = 128(M) x 64(N)

    // ---- staging addresses (global source pre-swizzled; LDS dest linear) ----
    int srow = l >> 3;                            // 0..7 row within 8-row gload slab
    int xcol = (l & 7) ^ srow;                    // swizzled 16B-slot index 0..7
    const __hip_bfloat16* aSrc = Mw + (size_t)(c0 + w * 32 + srow) * 1024 + xcol * 8;
    const __hip_bfloat16* bSrc = xmt + ((size_t)b << 20) + (size_t)(n0 + w * 32 + srow) * 1024 + xcol * 8;
    int stBase = w * 4096;                        // byte base of this wave's 32-row slab

    // ---- ds_read offsets (swizzled) ----
    int xs_ = (l & 7) << 4;
    int cb = (l >> 4) << 4;                       // 0,16,32,48
    int x0 = cb ^ xs_;                            // ks=0 column bytes
    int x1 = (64 | cb) ^ xs_;                     // ks=1 column bytes
    int aRow128 = (wr * 128 + (l & 15)) * 128;    // byte base of A fragment row
    int bRow128 = (wc * 64 + (l & 15)) * 128;     // byte base of B fragment row

    char* AsB = (char*)As;
    char* BsB = (char*)Bs;
    f32x4 acc[8][4] = {};

    #define STAGE_PH(nbuf, ph) do {                                                   \
        gload_lds16(aSrc + (ph) * 8192, AsB + (nbuf) * TSZ + stBase + (ph) * 1024);   \
        gload_lds16(bSrc + (ph) * 8192, BsB + (nbuf) * TSZ + stBase + (ph) * 1024);   \
    } while (0)

    #define TILE(curb, PREF) do {                                                     \
        _Pragma("unroll")                                                             \
        for (int ks = 0; ks < 2; ++ks) {                                              \
            int xk = ks ? x1 : x0;                                                    \
            bf16x8 bfr[4];                                                            \
            _Pragma("unroll")                                                         \
            for (int n = 0; n < 4; ++n)                                               \
                bfr[n] = *(const bf16x8*)(BsB + (curb) * TSZ + bRow128 + n * 2048 + xk); \
            _Pragma("unroll")                                                         \
            for (int mh = 0; mh < 2; ++mh) {                                          \
                bf16x8 af[4];                                                         \
                _Pragma("unroll")                                                     \
                for (int mi = 0; mi < 4; ++mi)                                        \
                    af[mi] = *(const bf16x8*)(AsB + (curb) * TSZ + aRow128 + (mh * 4 + mi) * 2048 + xk); \
                if (PREF) STAGE_PH((curb) ^ 1, ks * 2 + mh);                          \
                __builtin_amdgcn_s_setprio(1);                                        \
                _Pragma("unroll")                                                     \
                for (int mi = 0; mi < 4; ++mi)                                        \
                    _Pragma("unroll")                                                 \
                    for (int n = 0; n < 4; ++n)                                       \
                        acc[mh * 4 + mi][n] = __builtin_amdgcn_mfma_f32_16x16x32_bf16( \
                            af[mi], bfr[n], acc[mh * 4 + mi][n], 0, 0, 0);            \
                __builtin_amdgcn_s_setprio(0);                                        \
            }                                                                         \
        }                                                                             \
    } while (0)

    #define SYNC_ADV() do {                                                           \
        aSrc += 64; bSrc += 64;                                                       \
        asm volatile("s_waitcnt vmcnt(0)" ::: "memory");                              \
        __builtin_amdgcn_s_barrier();                                                 \
        __builtin_amdgcn_sched_barrier(0);                                            \
    } while (0)

    // prologue: stage tile 0 into buf 0
    #pragma unroll
    for (int ph = 0; ph < 4; ++ph) STAGE_PH(0, ph);
    SYNC_ADV();

    // main loop: 16 K-tiles (K=1024, BK=64), compile-time buffer parity
    #pragma unroll 1
    for (int t = 0; t < 7; ++t) {
        TILE(0, 1); SYNC_ADV();
        TILE(1, 1); SYNC_ADV();
    }
    TILE(0, 1); SYNC_ADV();
    TILE(1, 0);

    #undef STAGE_PH
    #undef TILE
    #undef SYNC_ADV

    // epilogue: C/D layout col = l&15, row = (l>>4)*4 + j
    int col = l & 15, rg = l >> 4;
    const float* xb = x + ((size_t)b << 20);
    float* ob = out + ((size_t)b << 20);
    #pragma unroll
    for (int mi = 0; mi < 8; ++mi) {
        #pragma unroll
        for (int j = 0; j < 4; ++j) {
            int gc = c0 + wr * 128 + mi * 16 + rg * 4 + j;
            float iv = inv[gc], sh = shift[gc];
            size_t rowoff = (size_t)gc * 1024 + n0 + wc * 64 + col;
            #pragma unroll
            for (int n = 0; n < 4; ++n) {
                size_t idx = rowoff + n * 16;
                ob[idx] = acc[mi][n][j] * iv + sh + xb[idx];
            }
        }
    }
}

extern "C" void kernel_launch(void* const* d_in, const int* in_sizes, int n_in,
                              void* d_out, int out_size, void* d_ws, size_t ws_size,
                              hipStream_t stream) {
    const float* x    = (const float*)d_in[0];
    const float* g_w  = (const float*)d_in[1];
    const float* g_b  = (const float*)d_in[2];
    const float* th_w = (const float*)d_in[3];
    const float* th_b = (const float*)d_in[4];
    const float* ph_w = (const float*)d_in[5];
    const float* ph_b = (const float*)d_in[6];
    const float* w_w  = (const float*)d_in[7];
    const float* w_b  = (const float*)d_in[8];
    const float* gam  = (const float*)d_in[9];
    const float* bet  = (const float*)d_in[10];
    const float* mea  = (const float*)d_in[11];
    const float* var  = (const float*)d_in[12];
    float* out = (float*)d_out;
    char* ws = (char*)d_ws;

    __hip_bfloat16* xmt = (__hip_bfloat16*)ws;                    // 64 MiB (written by mix, late)
    __hip_bfloat16* Mw  = (__hip_bfloat16*)(ws + 67108864);       // 2 MiB
    float* xbar  = (float*)(ws + 69206016);                       // 1 MiB
    float* theta = (float*)(ws + 70254592);                       // 512 KiB
    float* phi   = (float*)(ws + 70778880);                       // 512 KiB
    float* attn  = (float*)(ws + 71303168);                       // 8 KiB
    float* inv   = (float*)(ws + 71311360);                       // 4 KiB
    float* shift = (float*)(ws + 71315456);                       // 4 KiB
    // gwt/wwb overlay the xmt region: consumed by prepM_mfma BEFORE mix writes xmt
    __hip_bfloat16* gwt = (__hip_bfloat16*)ws;                    // 1 MiB
    __hip_bfloat16* wwb = (__hip_bfloat16*)(ws + 1048576);        // 1 MiB

    hipLaunchKernelGGL(pool_kernel, dim3(16384), dim3(256), 0, stream, x, xbar);
    hipLaunchKernelGGL(thetaphi_kernel, dim3(1024), dim3(256), 0, stream,
                       xbar, th_w, th_b, ph_w, ph_b, theta, phi);
    hipLaunchKernelGGL(attn_kernel, dim3(32), dim3(64), 0, stream, theta, phi, attn);
    hipLaunchKernelGGL(prep_operands_kernel, dim3(768), dim3(256), 0, stream,
                       g_w, w_w, gwt, wwb);
    hipLaunchKernelGGL(prepM_mfma_kernel, dim3(64), dim3(256), 0, stream, wwb, gwt, Mw);
    hipLaunchKernelGGL(prepbias_kernel, dim3(32), dim3(256), 0, stream,
                       w_w, g_b, w_b, gam, bet, mea, var, inv, shift);
    hipLaunchKernelGGL(mix_kernel, dim3(512), dim3(256), 0, stream, x, attn, xmt);
    hipLaunchKernelGGL(gemm256_kernel, dim3(512), dim3(512), 0, stream,
                       Mw, xmt, x, inv, shift, out);
}

// Round 5
// 238.223 us; speedup vs baseline: 2.2440x; 1.0442x over previous
//
#include <hip/hip_runtime.h>
#include <hip/hip_bf16.h>

typedef __attribute__((ext_vector_type(8))) short bf16x8;
typedef __attribute__((ext_vector_type(4))) float f32x4;

// ---------------------------------------------------------------- pool: xbar[b][c][t] = mean_hw x
__global__ __launch_bounds__(256) void pool_kernel(const float* __restrict__ x,
                                                   float* __restrict__ xbar) {
    int row = blockIdx.x * 16 + (threadIdx.x >> 4);   // (b*1024+c)*8+t
    int j = threadIdx.x & 15;
    const float4* p = (const float4*)(x + (size_t)row * 128);
    float4 a = p[j * 2], b2 = p[j * 2 + 1];
    float s = a.x + a.y + a.z + a.w + b2.x + b2.y + b2.z + b2.w;
    s += __shfl_xor(s, 1); s += __shfl_xor(s, 2);
    s += __shfl_xor(s, 4); s += __shfl_xor(s, 8);
    if (j == 0) xbar[row] = s * (1.0f / 128.0f);
}

// ------------------------------------------- theta/phi: [b][ic][t] = W @ xbar[b][:][t] + bias
__global__ __launch_bounds__(256) void thetaphi_kernel(
        const float* __restrict__ xbar,
        const float* __restrict__ tw, const float* __restrict__ tb,
        const float* __restrict__ pw, const float* __restrict__ pb,
        float* __restrict__ theta, float* __restrict__ phi) {
    int which = blockIdx.x & 1;
    int icc = (blockIdx.x >> 1) & 15;
    int b = blockIdx.x >> 5;
    const float* w = which ? pw : tw;
    const float* bias = which ? pb : tb;
    float* out = which ? phi : theta;
    __shared__ float xs[8192];
    for (int i = threadIdx.x; i < 8192; i += 256) xs[i] = xbar[b * 8192 + i];
    __syncthreads();
    int icl = threadIdx.x >> 3;
    int t = threadIdx.x & 7;
    int ic = icc * 32 + icl;
    const float* wr = w + (size_t)ic * 1024;
    float acc = 0.0f;
    #pragma unroll 8
    for (int k = 0; k < 1024; k++) acc += wr[k] * xs[k * 8 + t];
    out[((size_t)b * 512 + ic) * 8 + t] = acc + bias[ic];
}

// ------------------------------------------------------- attn[b][t][s] = softmax_s(theta.phi)
__global__ __launch_bounds__(64) void attn_kernel(const float* __restrict__ theta,
                                                  const float* __restrict__ phi,
                                                  float* __restrict__ attn) {
    __shared__ float th[4096], ph[4096];
    int b = blockIdx.x, lane = threadIdx.x;
    for (int i = lane; i < 4096; i += 64) {
        th[i] = theta[(size_t)b * 4096 + i];
        ph[i] = phi[(size_t)b * 4096 + i];
    }
    __syncthreads();
    int t = lane >> 3, s = lane & 7;
    float f = 0.0f;
    #pragma unroll 8
    for (int ic = 0; ic < 512; ic++) f += th[ic * 8 + t] * ph[ic * 8 + s];
    float m = f;
    m = fmaxf(m, __shfl_xor(m, 1));
    m = fmaxf(m, __shfl_xor(m, 2));
    m = fmaxf(m, __shfl_xor(m, 4));
    float e = __expf(f - m);
    float sum = e;
    sum += __shfl_xor(sum, 1); sum += __shfl_xor(sum, 2); sum += __shfl_xor(sum, 4);
    attn[b * 64 + lane] = e / sum;
}

// --------------------------- prep: gwt[cin][ic] = bf16(g_w[ic][cin]); wwb = bf16(w_w)
__global__ __launch_bounds__(256) void prep_operands_kernel(
        const float* __restrict__ gw, const float* __restrict__ ww,
        __hip_bfloat16* __restrict__ gwt, __hip_bfloat16* __restrict__ wwb) {
    int bid = blockIdx.x;
    if (bid < 512) {
        int icb = bid >> 5;            // 0..15
        int cb = bid & 31;             // 0..31
        __shared__ float tile[32][33];
        int r = threadIdx.x >> 5, c = threadIdx.x & 31;   // 8 x 32
        #pragma unroll
        for (int i = 0; i < 4; i++)
            tile[r + i * 8][c] = gw[(size_t)(icb * 32 + r + i * 8) * 1024 + cb * 32 + c];
        __syncthreads();
        #pragma unroll
        for (int i = 0; i < 4; i++) {
            int cin = cb * 32 + r + i * 8;
            gwt[(size_t)cin * 512 + icb * 32 + c] = __float2bfloat16(tile[c][r + i * 8]);
        }
    } else {
        int b2 = bid - 512;
        size_t base = (size_t)b2 * 2048 + (size_t)threadIdx.x * 8;
        const float4* src = (const float4*)(ww + base);
        float4 v0 = src[0], v1 = src[1];
        __hip_bfloat16 tmp[8];
        tmp[0] = __float2bfloat16(v0.x); tmp[1] = __float2bfloat16(v0.y);
        tmp[2] = __float2bfloat16(v0.z); tmp[3] = __float2bfloat16(v0.w);
        tmp[4] = __float2bfloat16(v1.x); tmp[5] = __float2bfloat16(v1.y);
        tmp[6] = __float2bfloat16(v1.z); tmp[7] = __float2bfloat16(v1.w);
        *(bf16x8*)(wwb + base) = *(const bf16x8*)tmp;
    }
}

#if defined(__has_builtin)
#if __has_builtin(__builtin_amdgcn_global_load_lds)
#define USE_GLOAD_LDS 1
#endif
#endif

__device__ __forceinline__ void gload_lds16(const void* g, void* ldsbase) {
#ifdef USE_GLOAD_LDS
    __builtin_amdgcn_global_load_lds(
        (__attribute__((address_space(1))) void*)(g),
        (__attribute__((address_space(3))) void*)(ldsbase), 16, 0, 0);
#endif
}

// --------------------------- prepM via MFMA: M[c][cin] = sum_k wwb[c][k]*gwt[cin][k]
__global__ __launch_bounds__(256) void prepM_mfma_kernel(
        const __hip_bfloat16* __restrict__ wwb,   // [1024][512]
        const __hip_bfloat16* __restrict__ gwt,   // [1024][512]
        __hip_bfloat16* __restrict__ M) {
    __shared__ __align__(16) __hip_bfloat16 As[128 * 32];
    __shared__ __align__(16) __hip_bfloat16 Bs[128 * 32];
    int bid = blockIdx.x;
    int mb = bid >> 3, nb = bid & 7;
    int c0 = mb * 128, n0 = nb * 128;
    int tid = threadIdx.x;
    int w = tid >> 6, l = tid & 63;
    int wr = w >> 1, wc = w & 1;
    const __hip_bfloat16* Ab = wwb + (size_t)c0 * 512;
    const __hip_bfloat16* Bb = gwt + (size_t)n0 * 512;
    int arow = tid >> 2, akq = tid & 3;
    f32x4 acc[4][4] = {};

    for (int kk = 0; kk < 16; ++kk) {
        int k0 = kk * 32;
#ifdef USE_GLOAD_LDS
        gload_lds16(Ab + (size_t)arow * 512 + k0 + akq * 8,        (char*)As + w * 1024);
        gload_lds16(Ab + (size_t)(arow + 64) * 512 + k0 + akq * 8, (char*)As + 4096 + w * 1024);
        gload_lds16(Bb + (size_t)arow * 512 + k0 + akq * 8,        (char*)Bs + w * 1024);
        gload_lds16(Bb + (size_t)(arow + 64) * 512 + k0 + akq * 8, (char*)Bs + 4096 + w * 1024);
#else
        *(bf16x8*)((char*)As + (size_t)tid * 16)        = *(const bf16x8*)(Ab + (size_t)arow * 512 + k0 + akq * 8);
        *(bf16x8*)((char*)As + 4096 + (size_t)tid * 16) = *(const bf16x8*)(Ab + (size_t)(arow + 64) * 512 + k0 + akq * 8);
        *(bf16x8*)((char*)Bs + (size_t)tid * 16)        = *(const bf16x8*)(Bb + (size_t)arow * 512 + k0 + akq * 8);
        *(bf16x8*)((char*)Bs + 4096 + (size_t)tid * 16) = *(const bf16x8*)(Bb + (size_t)(arow + 64) * 512 + k0 + akq * 8);
#endif
        __syncthreads();
        const __hip_bfloat16* Ap = As + ((size_t)(wr * 64 + (l & 15)) * 32) + (l >> 4) * 8;
        const __hip_bfloat16* Bp = Bs + ((size_t)(wc * 64 + (l & 15)) * 32) + (l >> 4) * 8;
        bf16x8 af[4], bfr[4];
        #pragma unroll
        for (int m = 0; m < 4; m++) af[m] = *(const bf16x8*)(Ap + m * 16 * 32);
        #pragma unroll
        for (int n = 0; n < 4; n++) bfr[n] = *(const bf16x8*)(Bp + n * 16 * 32);
        #pragma unroll
        for (int m = 0; m < 4; m++)
            #pragma unroll
            for (int n = 0; n < 4; n++)
                acc[m][n] = __builtin_amdgcn_mfma_f32_16x16x32_bf16(af[m], bfr[n], acc[m][n], 0, 0, 0);
        __syncthreads();
    }

    int col = l & 15, rg = l >> 4;
    #pragma unroll
    for (int m = 0; m < 4; m++)
        #pragma unroll
        for (int j = 0; j < 4; j++) {
            int gc = c0 + wr * 64 + m * 16 + rg * 4 + j;
            #pragma unroll
            for (int n = 0; n < 4; n++)
                M[(size_t)gc * 1024 + n0 + wc * 64 + n * 16 + col] = __float2bfloat16(acc[m][n][j]);
        }
}

// ---------------- per-channel epilogue constants inv[c], shift[c] (wave-parallel dot)
__global__ __launch_bounds__(256) void prepbias_kernel(
        const float* __restrict__ ww, const float* __restrict__ gb,
        const float* __restrict__ wb, const float* __restrict__ gamma,
        const float* __restrict__ beta, const float* __restrict__ mean,
        const float* __restrict__ var, float* __restrict__ inv,
        float* __restrict__ shift) {
    int wv = threadIdx.x >> 6, l = threadIdx.x & 63;
    int c = blockIdx.x * 32 + wv * 8 + (l >> 3);   // 32 blocks x 32 channels
    int j = l & 7;
    const float* wr = ww + (size_t)c * 512;
    float acc = 0.0f;
    #pragma unroll 8
    for (int k = j; k < 512; k += 8) acc += wr[k] * gb[k];
    acc += __shfl_xor(acc, 1); acc += __shfl_xor(acc, 2); acc += __shfl_xor(acc, 4);
    if (j == 0) {
        float cb = wb[c] + acc;
        float iv = gamma[c] * rsqrtf(var[c] + 1e-5f);
        inv[c] = iv;
        shift[c] = cb * iv + beta[c] - mean[c] * iv;
    }
}

// ------------- mix + transpose: xm_t[b][t*128+hw][c] (bf16) = sum_s attn[b][t][s]*x[b][c][s][hw]
__global__ __launch_bounds__(256) void mix_kernel(const float* __restrict__ x,
                                                  const float* __restrict__ attn,
                                                  __hip_bfloat16* __restrict__ xmt) {
    int orig = blockIdx.x;
    int wg = (orig & 7) * 64 + (orig >> 3);
    int b = wg >> 4;
    int hwg = wg & 15;                          // group of 8 hw positions
    __shared__ float at[64];
    __shared__ float xs[8][8][33];              // [s][h][ci], ci-dim padded to 33
    int tid = threadIdx.x;
    if (tid < 64) at[tid] = attn[b * 64 + tid];
    int ci = tid >> 3, s = tid & 7;             // staging role: 32 c x 8 s
    int h = tid >> 5, cq = tid & 31;            // compute role: 8 h x 32 c
    const float* xb = x + ((size_t)b << 20);
    __hip_bfloat16* ob = xmt + ((size_t)b << 20);
    for (int cc = 0; cc < 32; ++cc) {
        const float4* src = (const float4*)(xb + ((size_t)(cc * 32 + ci) * 8 + s) * 128 + hwg * 8);
        float4 v0 = src[0], v1 = src[1];
        __syncthreads();
        xs[s][0][ci] = v0.x; xs[s][1][ci] = v0.y; xs[s][2][ci] = v0.z; xs[s][3][ci] = v0.w;
        xs[s][4][ci] = v1.x; xs[s][5][ci] = v1.y; xs[s][6][ci] = v1.z; xs[s][7][ci] = v1.w;
        __syncthreads();
        float xr[8];
        #pragma unroll
        for (int ss = 0; ss < 8; ss++) xr[ss] = xs[ss][h][cq];
        #pragma unroll
        for (int t = 0; t < 8; t++) {
            float o = 0.0f;
            #pragma unroll
            for (int ss = 0; ss < 8; ss++) o += at[t * 8 + ss] * xr[ss];
            ob[(size_t)(t * 128 + hwg * 8 + h) * 1024 + cc * 32 + cq] = __float2bfloat16(o);
        }
    }
}

// ========== 256x256-tile / 8-wave GEMM, half-K(32) pipeline with counted vmcnt ==========
// out[b][c][n] = inv[c] * sum_k M[c][k]*xmt[b][n][k] + shift[c] + x[b][c][n]
// LDS: 4 half-buffers x (A 256x32 + B 256x32) bf16 = 128 KiB.
// 32 half-steps; step h: issue half h+3 (4 gloads/thread), ds_read+32 MFMA on half h,
// wait vmcnt(8) (= 2 halves outstanding), s_barrier. Loads get ~2.5 steps in flight.
// Swizzle: slot' = (slot + (row>>1)) & 3 within each 64B row (2-way bank quads = free),
// realized as pre-swizzled GLOBAL source + swizzled ds_read (both-sides, rule #21).
__global__ __launch_bounds__(512, 2) void gemm256_kernel(
        const __hip_bfloat16* __restrict__ Mw,    // [1024][1024]  (c, k)
        const __hip_bfloat16* __restrict__ xmt,   // [32][1024][1024] (n, k)
        const float* __restrict__ x,              // [32][1024][1024] (c, n)
        const float* __restrict__ inv, const float* __restrict__ shift,
        float* __restrict__ out) {
    __shared__ __align__(16) __hip_bfloat16 HBs[65536];        // 128 KiB = 4 x 32 KiB
    char* AH = (char*)HBs;
    const int BUFB = 32768;                                    // bytes per half-buffer

    int orig = blockIdx.x;
    int bid = (orig & 7) * 64 + (orig >> 3);      // XCD-chunked swizzle (512 % 8 == 0)
    int b = bid >> 4;
    int mb = (bid >> 2) & 3;
    int nb = bid & 3;
    int c0 = mb * 256, n0 = nb * 256;

    int tid = threadIdx.x;
    int w = tid >> 6, l = tid & 63;
    int wr = w >> 2, wc = w & 3;                  // 2 x 4 wave grid; wave out = 128(M) x 64(N)

    // ---- staging: lane l covers row w*16 + (l>>2), linear LDS slot l&3,
    //      global slot s = ((l&3) - ((l>>3)&3)) & 3  (inverse of slot' = (s + (row>>1))&3)
    int sgl = (((l & 3) - ((l >> 3) & 3)) & 3);
    const __hip_bfloat16* aS = Mw + (size_t)(c0 + w * 16 + (l >> 2)) * 1024 + sgl * 8;
    const __hip_bfloat16* bS = xmt + ((size_t)b << 20) + (size_t)(n0 + w * 16 + (l >> 2)) * 1024 + sgl * 8;
    int stBase = w * 1024;                        // byte base within half-region (wave slab)

    // ---- ds_read: slot = ((l>>4) + (((l&15)>>1)&3)) & 3, fragment adds 1024B (16 rows)
    int rdSlot = ((l >> 4) + (((l & 15) >> 1) & 3)) & 3;
    int aRdBase = (wr * 128 + (l & 15)) * 64 + rdSlot * 16;
    int bRdBase = 16384 + (wc * 64 + (l & 15)) * 64 + rdSlot * 16;

    f32x4 acc[8][4] = {};

    #define ISSUE(q3) do {                                                      \
        gload_lds16(aS,              AH + (q3) * BUFB + stBase);                \
        gload_lds16(aS + 128 * 1024, AH + (q3) * BUFB + stBase + 8192);         \
        gload_lds16(bS,              AH + (q3) * BUFB + 16384 + stBase);        \
        gload_lds16(bS + 128 * 1024, AH + (q3) * BUFB + 16384 + stBase + 8192); \
        aS += 32; bS += 32;                                                     \
    } while (0)

    #define V8 asm volatile("s_waitcnt vmcnt(8)" ::: "memory")
    #define V4 asm volatile("s_waitcnt vmcnt(4)" ::: "memory")
    #define V0 asm volatile("s_waitcnt vmcnt(0)" ::: "memory")

    #define HSTEP(q, DOISS, WAITM, LAST) do {                                   \
        if (DOISS) ISSUE(((q) + 3) & 3);                                        \
        const char* bufA = AH + (q) * BUFB;                                     \
        bf16x8 bfr[4];                                                          \
        _Pragma("unroll")                                                       \
        for (int n = 0; n < 4; ++n)                                             \
            bfr[n] = *(const bf16x8*)(bufA + bRdBase + n * 1024);               \
        __builtin_amdgcn_s_setprio(1);                                          \
        _Pragma("unroll")                                                       \
        for (int mi = 0; mi < 8; ++mi) {                                        \
            bf16x8 af = *(const bf16x8*)(bufA + aRdBase + mi * 1024);           \
            _Pragma("unroll")                                                   \
            for (int n = 0; n < 4; ++n)                                         \
                acc[mi][n] = __builtin_amdgcn_mfma_f32_16x16x32_bf16(           \
                    af, bfr[n], acc[mi][n], 0, 0, 0);                           \
        }                                                                       \
        __builtin_amdgcn_s_setprio(0);                                          \
        if (!LAST) {                                                            \
            WAITM;                                                              \
            __builtin_amdgcn_s_barrier();                                       \
            __builtin_amdgcn_sched_barrier(0);                                  \
        }                                                                       \
    } while (0)

    // prologue: issue halves 0,1,2 into bufs 0,1,2 (12 loads/thread)
    ISSUE(0); ISSUE(1); ISSUE(2);
    V8;                                           // half 0 landed (8 = halves 1,2 in flight)
    __builtin_amdgcn_s_barrier();
    __builtin_amdgcn_sched_barrier(0);

    // main: halves 0..27 (7 x 4), each issues half h+3
    #pragma unroll 1
    for (int t = 0; t < 7; ++t) {
        HSTEP(0, 1, V8, 0);
        HSTEP(1, 1, V8, 0);
        HSTEP(2, 1, V8, 0);
        HSTEP(3, 1, V8, 0);
    }
    HSTEP(0, 1, V8, 0);    // h=28, issues half 31 (last)
    HSTEP(1, 0, V4, 0);    // h=29
    HSTEP(2, 0, V0, 0);    // h=30
    HSTEP(3, 0, V0, 1);    // h=31 (no wait/barrier)

    #undef ISSUE
    #undef HSTEP
    #undef V8
    #undef V4
    #undef V0

    // epilogue: C/D layout col = l&15, row = (l>>4)*4 + j
    int col = l & 15, rg = l >> 4;
    const float* xb = x + ((size_t)b << 20);
    float* ob = out + ((size_t)b << 20);
    #pragma unroll
    for (int mi = 0; mi < 8; ++mi) {
        #pragma unroll
        for (int j = 0; j < 4; ++j) {
            int gc = c0 + wr * 128 + mi * 16 + rg * 4 + j;
            float iv = inv[gc], sh = shift[gc];
            size_t rowoff = (size_t)gc * 1024 + n0 + wc * 64 + col;
            #pragma unroll
            for (int n = 0; n < 4; ++n) {
                size_t idx = rowoff + n * 16;
                ob[idx] = acc[mi][n][j] * iv + sh + xb[idx];
            }
        }
    }
}

extern "C" void kernel_launch(void* const* d_in, const int* in_sizes, int n_in,
                              void* d_out, int out_size, void* d_ws, size_t ws_size,
                              hipStream_t stream) {
    const float* x    = (const float*)d_in[0];
    const float* g_w  = (const float*)d_in[1];
    const float* g_b  = (const float*)d_in[2];
    const float* th_w = (const float*)d_in[3];
    const float* th_b = (const float*)d_in[4];
    const float* ph_w = (const float*)d_in[5];
    const float* ph_b = (const float*)d_in[6];
    const float* w_w  = (const float*)d_in[7];
    const float* w_b  = (const float*)d_in[8];
    const float* gam  = (const float*)d_in[9];
    const float* bet  = (const float*)d_in[10];
    const float* mea  = (const float*)d_in[11];
    const float* var  = (const float*)d_in[12];
    float* out = (float*)d_out;
    char* ws = (char*)d_ws;

    __hip_bfloat16* xmt = (__hip_bfloat16*)ws;                    // 64 MiB (written by mix, late)
    __hip_bfloat16* Mw  = (__hip_bfloat16*)(ws + 67108864);       // 2 MiB
    float* xbar  = (float*)(ws + 69206016);                       // 1 MiB
    float* theta = (float*)(ws + 70254592);                       // 512 KiB
    float* phi   = (float*)(ws + 70778880);                       // 512 KiB
    float* attn  = (float*)(ws + 71303168);                       // 8 KiB
    float* inv   = (float*)(ws + 71311360);                       // 4 KiB
    float* shift = (float*)(ws + 71315456);                       // 4 KiB
    // gwt/wwb overlay the xmt region: consumed by prepM_mfma BEFORE mix writes xmt
    __hip_bfloat16* gwt = (__hip_bfloat16*)ws;                    // 1 MiB
    __hip_bfloat16* wwb = (__hip_bfloat16*)(ws + 1048576);        // 1 MiB

    hipLaunchKernelGGL(pool_kernel, dim3(16384), dim3(256), 0, stream, x, xbar);
    hipLaunchKernelGGL(thetaphi_kernel, dim3(1024), dim3(256), 0, stream,
                       xbar, th_w, th_b, ph_w, ph_b, theta, phi);
    hipLaunchKernelGGL(attn_kernel, dim3(32), dim3(64), 0, stream, theta, phi, attn);
    hipLaunchKernelGGL(prep_operands_kernel, dim3(768), dim3(256), 0, stream,
                       g_w, w_w, gwt, wwb);
    hipLaunchKernelGGL(prepM_mfma_kernel, dim3(64), dim3(256), 0, stream, wwb, gwt, Mw);
    hipLaunchKernelGGL(prepbias_kernel, dim3(32), dim3(256), 0, stream,
                       w_w, g_b, w_b, gam, bet, mea, var, inv, shift);
    hipLaunchKernelGGL(mix_kernel, dim3(512), dim3(256), 0, stream, x, attn, xmt);
    hipLaunchKernelGGL(gemm256_kernel, dim3(512), dim3(512), 0, stream,
                       Mw, xmt, x, inv, shift, out);
}